// Round 7
// baseline (41.667 us; speedup 1.0000x reference)
//
#include <hip/hip_runtime.h>

#define NPERS 64
#define NJOINT 15
#define NDEPTH 128
#define BIGF 100000.0f
#define EPSF 1e-8f
#define COEF_STRIDE 48   // floats per (b,q): w[15],c | wx[15],pad | wy[15],pad

// component j (0..14) of a 16-float group held in float4 a[base..base+3];
// j is a compile-time constant after unroll, so this folds to a register.
#define CELEM(a, base, j) \
    (((j) & 3) == 0 ? a[(base) + ((j) >> 2)].x : \
     ((j) & 3) == 1 ? a[(base) + ((j) >> 2)].y : \
     ((j) & 3) == 2 ? a[(base) + ((j) >> 2)].z : a[(base) + ((j) >> 2)].w)

// ---------------- precompute: per-(b,q) matching coefficients ----------------
// w_j = vis*inv ; c = (sum (rx^2+ry^2)*vis)*inv ; wx_j = 2*vis*rx*inv ; wy_j = 2*vis*ry*inv
// dist(p,d,q) = sum_j P2_j*w_j + c - sum_j X_j*wx_j - sum_j Y_j*wy_j
__global__ __launch_bounds__(256) void coef_kernel(
    const float* __restrict__ p2d,   // (B,NP,NJ,2)
    const float* __restrict__ vis,   // (B,NP,NJ)
    float* __restrict__ coef,        // (B,NP,48)
    int total)                       // B*NPERS
{
    int t = blockIdx.x * 256 + threadIdx.x;
    if (t >= total) return;
    float v[NJOINT], rx[NJOINT], ry[NJOINT];
    float vs = 0.0f, t2 = 0.0f;
    #pragma unroll
    for (int j = 0; j < NJOINT; ++j) {
        v[j]  = vis[t * NJOINT + j];
        rx[j] = p2d[(t * NJOINT + j) * 2 + 0];
        ry[j] = p2d[(t * NJOINT + j) * 2 + 1];
        vs += v[j];
        t2 = fmaf(rx[j] * rx[j] + ry[j] * ry[j], v[j], t2);
    }
    float inv = 1.0f / (vs + EPSF);
    float* o = coef + (size_t)t * COEF_STRIDE;
    #pragma unroll
    for (int j = 0; j < NJOINT; ++j) {
        o[j]      = v[j] * inv;
        o[16 + j] = 2.0f * v[j] * rx[j] * inv;
        o[32 + j] = 2.0f * v[j] * ry[j] * inv;
    }
    o[15] = t2 * inv;
    o[31] = 0.0f;
    o[47] = 0.0f;
}

// ---------------- main fused kernel ----------------
// One thread per (b,p,d). Coefficients stream through the VMEM pipe as
// uniform-address float4 loads (1 L1 transaction + broadcast per load),
// double-buffered cur/nxt so vmcnt-pipelining hides the latency under the
// 45-FMA inner body. No q-split: no duplicated projection, no LDS reduce.
__global__ __launch_bounds__(128, 2) void pose_match_kernel(
    const float* __restrict__ poses_3d,   // (B,NP,NJ,ND,3)
    const float* __restrict__ p2d,        // (B,NP,NJ,2)
    const float* __restrict__ vis,        // (B,NP,NJ)
    const int*   __restrict__ nper,       // (B,)
    const float* __restrict__ Rm,         // (B,3,3)
    const float* __restrict__ Tm,         // (B,3)
    const float* __restrict__ fm,         // (B,2)
    const float* __restrict__ cm,         // (B,2)
    const float* __restrict__ iw_,        // (B,)
    const float* __restrict__ ih_,        // (B,)
    const float* __restrict__ coef,       // (B,NP,48) packed coefficients
    float* __restrict__ out)              // (B,NP,NJ,ND)
{
    const int b = blockIdx.x >> 6;
    const int p = blockIdx.x & 63;
    const int d = threadIdx.x;            // 0..127

    __shared__ float4 sq[NPERS][NJOINT];  // {vis, rx, ry, _} -- phase-2 only

    // ---- stage per-batch candidate data into LDS (phase-2 lookup table) ----
    for (int i = threadIdx.x; i < NPERS * NJOINT; i += 128) {
        int q = i / NJOINT, j = i % NJOINT;
        float v  = vis[(b * NPERS + q) * NJOINT + j];
        float rx = p2d[((b * NPERS + q) * NJOINT + j) * 2 + 0];
        float ry = p2d[((b * NPERS + q) * NJOINT + j) * 2 + 1];
        sq[q][j] = make_float4(v, rx, ry, 0.0f);
    }
    __syncthreads();

    // ---- camera params (wave-uniform) ----
    const float R00 = Rm[b*9+0], R01 = Rm[b*9+1], R02 = Rm[b*9+2];
    const float R10 = Rm[b*9+3], R11 = Rm[b*9+4], R12 = Rm[b*9+5];
    const float R20 = Rm[b*9+6], R21 = Rm[b*9+7], R22 = Rm[b*9+8];
    const float T0 = Tm[b*3+0], T1 = Tm[b*3+1], T2 = Tm[b*3+2];
    const float fx = fm[b*2+0], fy = fm[b*2+1];
    const float cx = cm[b*2+0], cy = cm[b*2+1];
    const float iwm1 = iw_[b] - 1.0f;
    const float ihm1 = ih_[b] - 1.0f;
    const int   npv  = nper[b];

    // ---- project this thread's 15 joints (rcp: >=40px bound margin => safe) ----
    float X[NJOINT], Y[NJOINT], P2[NJOINT];
    #pragma unroll
    for (int j = 0; j < NJOINT; ++j) {
        int base = (((b * NPERS + p) * NJOINT + j) * NDEPTH + d) * 3;
        float a0 = poses_3d[base + 0] - T0;
        float a1 = poses_3d[base + 1] - T1;
        float a2 = poses_3d[base + 2] - T2;
        float xc0 = R00 * a0 + R01 * a1 + R02 * a2;
        float xc1 = R10 * a0 + R11 * a1 + R12 * a2;
        float xc2 = R20 * a0 + R21 * a1 + R22 * a2;
        float r   = __builtin_amdgcn_rcpf(xc2);
        float xx  = fmaf(fx * xc0, r, cx);
        float yy  = fmaf(fy * xc1, r, cy);
        X[j] = xx; Y[j] = yy;
        P2[j] = xx * xx + yy * yy;
    }

    // ---- argmin over all 64 candidates, coef double-buffered via VMEM ----
    const float4* cb4 = reinterpret_cast<const float4*>(
        coef + (size_t)(b * NPERS) * COEF_STRIDE);  // 12 float4 per q

    float4 cur[12], nxt[12];
    #pragma unroll
    for (int k = 0; k < 12; ++k) cur[k] = cb4[k];   // q = 0

    float bestv = 3.0e38f;
    int   bestq = 0;
    #pragma unroll 2
    for (int q = 0; q < NPERS; ++q) {
        const int qn = (q + 1) & 63;                // wrap: last prefetch unused
        #pragma unroll
        for (int k = 0; k < 12; ++k) nxt[k] = cb4[qn * 12 + k];

        float s1 = cur[3].w;                        // c term
        float sx = 0.0f, sy = 0.0f;
        #pragma unroll
        for (int j = 0; j < NJOINT; ++j) {
            s1 = fmaf(P2[j], CELEM(cur, 0, j), s1);
            sx = fmaf(X[j],  CELEM(cur, 4, j), sx);
            sy = fmaf(Y[j],  CELEM(cur, 8, j), sy);
        }
        float dist = s1 - sx - sy;
        dist = (q < npv) ? dist : BIGF;
        if (dist < bestv) { bestv = dist; bestq = q; }

        #pragma unroll
        for (int k = 0; k < 12; ++k) cur[k] = nxt[k];
    }

    // ---- phase 2: score against matched candidate ----
    const int obase = ((b * NPERS + p) * NJOINT) * NDEPTH + d;
    #pragma unroll
    for (int j = 0; j < NJOINT; ++j) {
        float4 v = sq[bestq][j];
        float dx = X[j] - v.y;
        float dy = Y[j] - v.z;
        float md = fmaf(dx, dx, dy * dy);
        float sc = __expf(-md * (1.0f / 225.0f));
        float inb = (X[j] >= 0.0f && Y[j] >= 0.0f &&
                     X[j] <= iwm1 && Y[j] <= ihm1) ? 1.0f : 0.0f;
        out[obase + j * NDEPTH] = sc * inb * v.x;
    }
}

extern "C" void kernel_launch(void* const* d_in, const int* in_sizes, int n_in,
                              void* d_out, int out_size, void* d_ws, size_t ws_size,
                              hipStream_t stream) {
    const float* poses_3d = (const float*)d_in[0];
    const float* p2d      = (const float*)d_in[1];
    const float* vis      = (const float*)d_in[2];
    const int*   nper     = (const int*)d_in[3];
    const float* Rm       = (const float*)d_in[4];
    const float* Tm       = (const float*)d_in[5];
    const float* fm       = (const float*)d_in[6];
    const float* cm       = (const float*)d_in[7];
    const float* iw       = (const float*)d_in[8];
    const float* ih       = (const float*)d_in[9];
    float* out  = (float*)d_out;
    float* coef = (float*)d_ws;            // B*NPERS*48 floats = 192 KiB

    const int B = in_sizes[3];  // num_persons_ref has B elements
    const int total = B * NPERS;

    coef_kernel<<<(total + 255) / 256, 256, 0, stream>>>(p2d, vis, coef, total);

    dim3 grid(B * NPERS);
    dim3 block(128);
    pose_match_kernel<<<grid, block, 0, stream>>>(
        poses_3d, p2d, vis, nper, Rm, Tm, fm, cm, iw, ih, coef, out);
}

// Round 8
// 32.992 us; speedup vs baseline: 1.2629x; 1.2629x over previous
//
#include <hip/hip_runtime.h>

#define NPERS 64
#define NJOINT 15
#define NDEPTH 128
#define BIGF 100000.0f
#define EPSF 1e-8f

// component j (0..15) of 16 floats held in float4 a[0..3]; j compile-time.
#define CELEM(a, j) \
    (((j) & 3) == 0 ? a[(j) >> 2].x : \
     ((j) & 3) == 1 ? a[(j) >> 2].y : \
     ((j) & 3) == 2 ? a[(j) >> 2].z : a[(j) >> 2].w)

// One block = (b, person-pair). Thread = depth bin d, holds projections for
// BOTH persons of the pair, so every broadcast coefficient read from LDS is
// amortized over 2 dist accumulations -> total LDS traffic halves vs R2.
// Coefficients are folded in-block from the staged sq table (no 2nd kernel).
__global__ __launch_bounds__(128, 1) void pose_match_kernel(
    const float* __restrict__ poses_3d,   // (B,NP,NJ,ND,3)
    const float* __restrict__ p2d,        // (B,NP,NJ,2)
    const float* __restrict__ vis,        // (B,NP,NJ)
    const int*   __restrict__ nper,       // (B,)
    const float* __restrict__ Rm,         // (B,3,3)
    const float* __restrict__ Tm,         // (B,3)
    const float* __restrict__ fm,         // (B,2)
    const float* __restrict__ cm,         // (B,2)
    const float* __restrict__ iw_,        // (B,)
    const float* __restrict__ ih_,        // (B,)
    float* __restrict__ out)              // (B,NP,NJ,ND)
{
    const int b  = blockIdx.x >> 5;       // 32 person-pairs per batch
    const int pp = blockIdx.x & 31;
    const int p0 = pp * 2;
    const int d  = threadIdx.x;           // 0..127

    __shared__ float4 sq[NPERS][NJOINT];  // {vis, rx, ry, _}  (phase 2)
    __shared__ float4 sco[NPERS][12];     // w[15],c | wx[15],0 | wy[15],0

    // ---- stage raw candidate data ----
    for (int i = threadIdx.x; i < NPERS * NJOINT; i += 128) {
        int q = i / NJOINT, j = i % NJOINT;
        float v  = vis[(b * NPERS + q) * NJOINT + j];
        float rx = p2d[((b * NPERS + q) * NJOINT + j) * 2 + 0];
        float ry = p2d[((b * NPERS + q) * NJOINT + j) * 2 + 1];
        sq[q][j] = make_float4(v, rx, ry, 0.0f);
    }
    __syncthreads();

    // ---- fold into matching coefficients (threads 0..63, one q each) ----
    // dist(p,d,q) = sum_j P2*w + c - sum_j X*wx - sum_j Y*wy
    if (threadIdx.x < NPERS) {
        const int q = threadIdx.x;
        float vs = 0.0f, t2 = 0.0f;
        #pragma unroll
        for (int j = 0; j < NJOINT; ++j) {
            float4 s = sq[q][j];
            vs += s.x;
            t2 = fmaf(s.y * s.y + s.z * s.z, s.x, t2);
        }
        float inv = 1.0f / (vs + EPSF);
        float* o = (float*)&sco[q][0];
        #pragma unroll
        for (int j = 0; j < NJOINT; ++j) {
            float4 s = sq[q][j];
            o[j]      = s.x * inv;
            o[16 + j] = 2.0f * s.x * s.y * inv;
            o[32 + j] = 2.0f * s.x * s.z * inv;
        }
        o[15] = t2 * inv;
        o[31] = 0.0f;
        o[47] = 0.0f;
    }
    __syncthreads();

    // ---- camera params (wave-uniform) ----
    const float R00 = Rm[b*9+0], R01 = Rm[b*9+1], R02 = Rm[b*9+2];
    const float R10 = Rm[b*9+3], R11 = Rm[b*9+4], R12 = Rm[b*9+5];
    const float R20 = Rm[b*9+6], R21 = Rm[b*9+7], R22 = Rm[b*9+8];
    const float T0 = Tm[b*3+0], T1 = Tm[b*3+1], T2 = Tm[b*3+2];
    const float fx = fm[b*2+0], fy = fm[b*2+1];
    const float cx = cm[b*2+0], cy = cm[b*2+1];
    const float iwm1 = iw_[b] - 1.0f;
    const float ihm1 = ih_[b] - 1.0f;
    const int   npv  = nper[b];

    // ---- project 15 joints for BOTH persons of the pair ----
    float X[2][NJOINT], Y[2][NJOINT], P2[2][NJOINT];
    #pragma unroll
    for (int pi = 0; pi < 2; ++pi) {
        #pragma unroll
        for (int j = 0; j < NJOINT; ++j) {
            int base = (((b * NPERS + p0 + pi) * NJOINT + j) * NDEPTH + d) * 3;
            float a0 = poses_3d[base + 0] - T0;
            float a1 = poses_3d[base + 1] - T1;
            float a2 = poses_3d[base + 2] - T2;
            float xc0 = R00 * a0 + R01 * a1 + R02 * a2;
            float xc1 = R10 * a0 + R11 * a1 + R12 * a2;
            float xc2 = R20 * a0 + R21 * a1 + R22 * a2;
            float r   = __builtin_amdgcn_rcpf(xc2);
            float xx  = fmaf(fx * xc0, r, cx);
            float yy  = fmaf(fy * xc1, r, cy);
            X[pi][j] = xx; Y[pi][j] = yy;
            P2[pi][j] = xx * xx + yy * yy;
        }
    }

    // ---- argmin over 64 candidates; each coef read feeds 2 persons ----
    float bestv0 = 3.0e38f, bestv1 = 3.0e38f;
    int   bestq0 = 0,       bestq1 = 0;
    #pragma unroll 2
    for (int q = 0; q < NPERS; ++q) {
        float4 cw[4], cxr[4], cyr[4];
        #pragma unroll
        for (int k = 0; k < 4; ++k) {
            cw[k]  = sco[q][k];
            cxr[k] = sco[q][4 + k];
            cyr[k] = sco[q][8 + k];
        }
        float s1a = cw[3].w, sxa = 0.0f, sya = 0.0f;
        float s1b = cw[3].w, sxb = 0.0f, syb = 0.0f;
        #pragma unroll
        for (int j = 0; j < NJOINT; ++j) {
            float w  = CELEM(cw,  j);
            float wx = CELEM(cxr, j);
            float wy = CELEM(cyr, j);
            s1a = fmaf(P2[0][j], w,  s1a);
            sxa = fmaf(X[0][j],  wx, sxa);
            sya = fmaf(Y[0][j],  wy, sya);
            s1b = fmaf(P2[1][j], w,  s1b);
            sxb = fmaf(X[1][j],  wx, sxb);
            syb = fmaf(Y[1][j],  wy, syb);
        }
        float d0 = s1a - sxa - sya;
        float d1 = s1b - sxb - syb;
        d0 = (q < npv) ? d0 : BIGF;
        d1 = (q < npv) ? d1 : BIGF;
        if (d0 < bestv0) { bestv0 = d0; bestq0 = q; }   // ascending q, strict <
        if (d1 < bestv1) { bestv1 = d1; bestq1 = q; }   // == np.argmin ties
    }

    // ---- phase 2: score against matched candidates ----
    #pragma unroll
    for (int pi = 0; pi < 2; ++pi) {
        const int bq = (pi == 0) ? bestq0 : bestq1;
        const int obase = ((b * NPERS + p0 + pi) * NJOINT) * NDEPTH + d;
        #pragma unroll
        for (int j = 0; j < NJOINT; ++j) {
            float4 v = sq[bq][j];
            float xx = X[pi][j], yy = Y[pi][j];
            float dx = xx - v.y;
            float dy = yy - v.z;
            float md = fmaf(dx, dx, dy * dy);
            float sc = __expf(-md * (1.0f / 225.0f));
            float inb = (xx >= 0.0f && yy >= 0.0f &&
                         xx <= iwm1 && yy <= ihm1) ? 1.0f : 0.0f;
            out[obase + j * NDEPTH] = sc * inb * v.x;
        }
    }
}

extern "C" void kernel_launch(void* const* d_in, const int* in_sizes, int n_in,
                              void* d_out, int out_size, void* d_ws, size_t ws_size,
                              hipStream_t stream) {
    const float* poses_3d = (const float*)d_in[0];
    const float* p2d      = (const float*)d_in[1];
    const float* vis      = (const float*)d_in[2];
    const int*   nper     = (const int*)d_in[3];
    const float* Rm       = (const float*)d_in[4];
    const float* Tm       = (const float*)d_in[5];
    const float* fm       = (const float*)d_in[6];
    const float* cm       = (const float*)d_in[7];
    const float* iw       = (const float*)d_in[8];
    const float* ih       = (const float*)d_in[9];
    float* out = (float*)d_out;

    const int B = in_sizes[3];  // num_persons_ref has B elements
    dim3 grid(B * 32);          // (b, person-pair)
    dim3 block(128);
    pose_match_kernel<<<grid, block, 0, stream>>>(
        poses_3d, p2d, vis, nper, Rm, Tm, fm, cm, iw, ih, out);
}

// Round 9
// 31.226 us; speedup vs baseline: 1.3344x; 1.0566x over previous
//
#include <hip/hip_runtime.h>

#define NPERS 64
#define NJOINT 15
#define NDEPTH 128
#define BIGF 100000.0f
#define EPSF 1e-8f
#define QS 4                 // q-split: 4 waves, 16 candidates each
#define QCHUNK (NPERS / QS)

// component j (0..15) of 16 floats held in float4 a[0..3]; j compile-time.
#define CELEM(a, j) \
    (((j) & 3) == 0 ? a[(j) >> 2].x : \
     ((j) & 3) == 1 ? a[(j) >> 2].y : \
     ((j) & 3) == 2 ? a[(j) >> 2].z : a[(j) >> 2].w)

// Register-blocked "GEMM": per thread a 2-person x 2-depth tile, so every
// broadcast coefficient read from LDS feeds 4 dist accumulations (393k b128
// total -> 7.7us LDS floor), with a 4-way q-split keeping 2 waves/SIMD for
// latency hiding (R8 lesson: tiling without occupancy stalls at ~2x floor).
// dist = sum_j X(wX-wx) + Y(wY-wy) + c  (P2 folded away -> 120 fewer VGPRs)
__global__ __launch_bounds__(256, 2) void pose_match_kernel(
    const float* __restrict__ poses_3d,   // (B,NP,NJ,ND,3)
    const float* __restrict__ p2d,        // (B,NP,NJ,2)
    const float* __restrict__ vis,        // (B,NP,NJ)
    const int*   __restrict__ nper,       // (B,)
    const float* __restrict__ Rm,         // (B,3,3)
    const float* __restrict__ Tm,         // (B,3)
    const float* __restrict__ fm,         // (B,2)
    const float* __restrict__ cm,         // (B,2)
    const float* __restrict__ iw_,        // (B,)
    const float* __restrict__ ih_,        // (B,)
    float* __restrict__ out)              // (B,NP,NJ,ND)
{
    const int b    = blockIdx.x >> 5;     // 32 person-pairs per batch
    const int pp   = blockIdx.x & 31;
    const int p0   = pp * 2;
    const int tid  = threadIdx.x;
    const int wv   = tid >> 6;            // wave id 0..3 == q-slice
    const int lane = tid & 63;            // d-pair index: d = lane, lane+64

    __shared__ float4 sq[NPERS][NJOINT];  // {vis, rx, ry, _}  (phase 2)
    __shared__ float4 sco[NPERS][12];     // w[15],c | wx[15],0 | wy[15],0
    __shared__ float  bvred[QS][4][64];   // [slice][combo][lane]
    __shared__ int    bqred[QS][4][64];

    // ---- stage raw candidate data ----
    for (int i = tid; i < NPERS * NJOINT; i += 256) {
        int q = i / NJOINT, j = i % NJOINT;
        float v  = vis[(b * NPERS + q) * NJOINT + j];
        float rx = p2d[((b * NPERS + q) * NJOINT + j) * 2 + 0];
        float ry = p2d[((b * NPERS + q) * NJOINT + j) * 2 + 1];
        sq[q][j] = make_float4(v, rx, ry, 0.0f);
    }
    __syncthreads();

    // ---- fold into matching coefficients (threads 0..63, one q each) ----
    if (tid < NPERS) {
        const int q = tid;
        float vs = 0.0f, t2 = 0.0f;
        #pragma unroll
        for (int j = 0; j < NJOINT; ++j) {
            float4 s = sq[q][j];
            vs += s.x;
            t2 = fmaf(s.y * s.y + s.z * s.z, s.x, t2);
        }
        float inv = 1.0f / (vs + EPSF);
        float* o = (float*)&sco[q][0];
        #pragma unroll
        for (int j = 0; j < NJOINT; ++j) {
            float4 s = sq[q][j];
            o[j]      = s.x * inv;
            o[16 + j] = 2.0f * s.x * s.y * inv;
            o[32 + j] = 2.0f * s.x * s.z * inv;
        }
        o[15] = t2 * inv;      // c term
        o[31] = 0.0f;
        o[47] = 0.0f;
    }
    __syncthreads();

    // ---- camera params (wave-uniform) ----
    const float R00 = Rm[b*9+0], R01 = Rm[b*9+1], R02 = Rm[b*9+2];
    const float R10 = Rm[b*9+3], R11 = Rm[b*9+4], R12 = Rm[b*9+5];
    const float R20 = Rm[b*9+6], R21 = Rm[b*9+7], R22 = Rm[b*9+8];
    const float T0 = Tm[b*3+0], T1 = Tm[b*3+1], T2 = Tm[b*3+2];
    const float fx = fm[b*2+0], fy = fm[b*2+1];
    const float cx = cm[b*2+0], cy = cm[b*2+1];
    const float iwm1 = iw_[b] - 1.0f;
    const float ihm1 = ih_[b] - 1.0f;
    const int   npv  = nper[b];

    // ---- project 15 joints for the 2x2 (person, depth-half) tile ----
    float X[2][2][NJOINT], Y[2][2][NJOINT];
    #pragma unroll
    for (int pi = 0; pi < 2; ++pi) {
        #pragma unroll
        for (int dh = 0; dh < 2; ++dh) {
            const int d = lane + dh * 64;
            #pragma unroll
            for (int j = 0; j < NJOINT; ++j) {
                int base = (((b * NPERS + p0 + pi) * NJOINT + j) * NDEPTH + d) * 3;
                float a0 = poses_3d[base + 0] - T0;
                float a1 = poses_3d[base + 1] - T1;
                float a2 = poses_3d[base + 2] - T2;
                float xc0 = R00 * a0 + R01 * a1 + R02 * a2;
                float xc1 = R10 * a0 + R11 * a1 + R12 * a2;
                float xc2 = R20 * a0 + R21 * a1 + R22 * a2;
                float r   = __builtin_amdgcn_rcpf(xc2);
                X[pi][dh][j] = fmaf(fx * xc0, r, cx);
                Y[pi][dh][j] = fmaf(fy * xc1, r, cy);
            }
        }
    }

    // ---- partial argmin: this wave's 16-candidate slice, 4 combos ----
    float bv00 = 3.0e38f, bv01 = 3.0e38f, bv10 = 3.0e38f, bv11 = 3.0e38f;
    int   bq00 = 0, bq01 = 0, bq10 = 0, bq11 = 0;
    const int q0 = wv * QCHUNK;
    #pragma unroll 2
    for (int q = q0; q < q0 + QCHUNK; ++q) {
        float4 cw[4], cxr[4], cyr[4];
        #pragma unroll
        for (int k = 0; k < 4; ++k) {
            cw[k]  = sco[q][k];
            cxr[k] = sco[q][4 + k];
            cyr[k] = sco[q][8 + k];
        }
        const float c = cw[3].w;
        float a00 = c, a01 = c, a10 = c, a11 = c;
        #pragma unroll
        for (int j = 0; j < NJOINT; ++j) {
            float w  = CELEM(cw,  j);
            float wx = CELEM(cxr, j);
            float wy = CELEM(cyr, j);
            float u;
            u = fmaf(w, X[0][0][j], -wx); a00 = fmaf(X[0][0][j], u, a00);
            u = fmaf(w, Y[0][0][j], -wy); a00 = fmaf(Y[0][0][j], u, a00);
            u = fmaf(w, X[0][1][j], -wx); a01 = fmaf(X[0][1][j], u, a01);
            u = fmaf(w, Y[0][1][j], -wy); a01 = fmaf(Y[0][1][j], u, a01);
            u = fmaf(w, X[1][0][j], -wx); a10 = fmaf(X[1][0][j], u, a10);
            u = fmaf(w, Y[1][0][j], -wy); a10 = fmaf(Y[1][0][j], u, a10);
            u = fmaf(w, X[1][1][j], -wx); a11 = fmaf(X[1][1][j], u, a11);
            u = fmaf(w, Y[1][1][j], -wy); a11 = fmaf(Y[1][1][j], u, a11);
        }
        if (q >= npv) { a00 = BIGF; a01 = BIGF; a10 = BIGF; a11 = BIGF; }
        if (a00 < bv00) { bv00 = a00; bq00 = q; }   // ascending q, strict <
        if (a01 < bv01) { bv01 = a01; bq01 = q; }
        if (a10 < bv10) { bv10 = a10; bq10 = q; }
        if (a11 < bv11) { bv11 = a11; bq11 = q; }
    }
    // combo index: pi*2 + dh
    bvred[wv][0][lane] = bv00;  bqred[wv][0][lane] = bq00;
    bvred[wv][1][lane] = bv01;  bqred[wv][1][lane] = bq01;
    bvred[wv][2][lane] = bv10;  bqred[wv][2][lane] = bq10;
    bvred[wv][3][lane] = bv11;  bqred[wv][3][lane] = bq11;
    __syncthreads();

    // ---- each wave finishes ONE combo: combine slices + epilogue ----
    const int pi = wv >> 1;
    const int dh = wv & 1;
    float bestv = 3.0e38f;
    int   bestq = 0;
    #pragma unroll
    for (int k = 0; k < QS; ++k) {          // ascending slice == ascending q
        float v = bvred[k][wv][lane];
        if (v < bestv) { bestv = v; bestq = bqred[k][wv][lane]; }
    }
    const int d = lane + dh * 64;
    const int obase = ((b * NPERS + p0 + pi) * NJOINT) * NDEPTH + d;
    #pragma unroll
    for (int j = 0; j < NJOINT; ++j) {
        float4 v = sq[bestq][j];
        float xx = X[pi][dh][j], yy = Y[pi][dh][j];
        float dx = xx - v.y;
        float dy = yy - v.z;
        float md = fmaf(dx, dx, dy * dy);
        float sc = __expf(-md * (1.0f / 225.0f));
        float inb = (xx >= 0.0f && yy >= 0.0f &&
                     xx <= iwm1 && yy <= ihm1) ? 1.0f : 0.0f;
        out[obase + j * NDEPTH] = sc * inb * v.x;
    }
}

extern "C" void kernel_launch(void* const* d_in, const int* in_sizes, int n_in,
                              void* d_out, int out_size, void* d_ws, size_t ws_size,
                              hipStream_t stream) {
    const float* poses_3d = (const float*)d_in[0];
    const float* p2d      = (const float*)d_in[1];
    const float* vis      = (const float*)d_in[2];
    const int*   nper     = (const int*)d_in[3];
    const float* Rm       = (const float*)d_in[4];
    const float* Tm       = (const float*)d_in[5];
    const float* fm       = (const float*)d_in[6];
    const float* cm       = (const float*)d_in[7];
    const float* iw       = (const float*)d_in[8];
    const float* ih       = (const float*)d_in[9];
    float* out = (float*)d_out;

    const int B = in_sizes[3];  // num_persons_ref has B elements
    dim3 grid(B * 32);          // (b, person-pair)
    dim3 block(256);            // 4 waves: q-slice x d-pair
    pose_match_kernel<<<grid, block, 0, stream>>>(
        poses_3d, p2d, vis, nper, Rm, Tm, fm, cm, iw, ih, out);
}

// Round 10
// 30.503 us; speedup vs baseline: 1.3660x; 1.0237x over previous
//
#include <hip/hip_runtime.h>

#define NPERS 64
#define NJOINT 15
#define NDEPTH 128
#define BIGF 100000.0f
#define EPSF 1e-8f
#define QS 4                 // q-split: 4 waves, 16 candidates each
#define QCHUNK (NPERS / QS)

// component j (0..15) of 16 floats held in float4 a[0..3]; j compile-time.
#define CELEM(a, j) \
    (((j) & 3) == 0 ? a[(j) >> 2].x : \
     ((j) & 3) == 1 ? a[(j) >> 2].y : \
     ((j) & 3) == 2 ? a[(j) >> 2].z : a[(j) >> 2].w)

// R9 + spill fix: ALL per-thread array indices are compile-time (rule #20).
// The epilogue statically unrolls the 4 (pi,dh) combos and predicates with
// the wave-uniform (wv == combo) so X/Y stay in VGPRs, not scratch.
__global__ __launch_bounds__(256, 2) void pose_match_kernel(
    const float* __restrict__ poses_3d,   // (B,NP,NJ,ND,3)
    const float* __restrict__ p2d,        // (B,NP,NJ,2)
    const float* __restrict__ vis,        // (B,NP,NJ)
    const int*   __restrict__ nper,       // (B,)
    const float* __restrict__ Rm,         // (B,3,3)
    const float* __restrict__ Tm,         // (B,3)
    const float* __restrict__ fm,         // (B,2)
    const float* __restrict__ cm,         // (B,2)
    const float* __restrict__ iw_,        // (B,)
    const float* __restrict__ ih_,        // (B,)
    float* __restrict__ out)              // (B,NP,NJ,ND)
{
    const int b    = blockIdx.x >> 5;     // 32 person-pairs per batch
    const int pp   = blockIdx.x & 31;
    const int p0   = pp * 2;
    const int tid  = threadIdx.x;
    const int wv   = tid >> 6;            // wave id 0..3 == q-slice
    const int lane = tid & 63;            // d = lane + dh*64

    __shared__ float4 sq[NPERS][NJOINT];  // {vis, rx, ry, _}  (phase 2)
    __shared__ float4 sco[NPERS][12];     // w[15],c | wx[15],0 | wy[15],0
    __shared__ float  bvred[QS][4][64];   // [slice][combo][lane]
    __shared__ int    bqred[QS][4][64];

    // ---- stage raw candidate data ----
    for (int i = tid; i < NPERS * NJOINT; i += 256) {
        int q = i / NJOINT, j = i % NJOINT;
        float v  = vis[(b * NPERS + q) * NJOINT + j];
        float rx = p2d[((b * NPERS + q) * NJOINT + j) * 2 + 0];
        float ry = p2d[((b * NPERS + q) * NJOINT + j) * 2 + 1];
        sq[q][j] = make_float4(v, rx, ry, 0.0f);
    }
    __syncthreads();

    // ---- fold into matching coefficients (threads 0..63, one q each) ----
    if (tid < NPERS) {
        const int q = tid;
        float vs = 0.0f, t2 = 0.0f;
        #pragma unroll
        for (int j = 0; j < NJOINT; ++j) {
            float4 s = sq[q][j];
            vs += s.x;
            t2 = fmaf(s.y * s.y + s.z * s.z, s.x, t2);
        }
        float inv = 1.0f / (vs + EPSF);
        float* o = (float*)&sco[q][0];
        #pragma unroll
        for (int j = 0; j < NJOINT; ++j) {
            float4 s = sq[q][j];
            o[j]      = s.x * inv;
            o[16 + j] = 2.0f * s.x * s.y * inv;
            o[32 + j] = 2.0f * s.x * s.z * inv;
        }
        o[15] = t2 * inv;      // c term
        o[31] = 0.0f;
        o[47] = 0.0f;
    }
    __syncthreads();

    // ---- camera params (wave-uniform) ----
    const float R00 = Rm[b*9+0], R01 = Rm[b*9+1], R02 = Rm[b*9+2];
    const float R10 = Rm[b*9+3], R11 = Rm[b*9+4], R12 = Rm[b*9+5];
    const float R20 = Rm[b*9+6], R21 = Rm[b*9+7], R22 = Rm[b*9+8];
    const float T0 = Tm[b*3+0], T1 = Tm[b*3+1], T2 = Tm[b*3+2];
    const float fx = fm[b*2+0], fy = fm[b*2+1];
    const float cx = cm[b*2+0], cy = cm[b*2+1];
    const float iwm1 = iw_[b] - 1.0f;
    const float ihm1 = ih_[b] - 1.0f;
    const int   npv  = nper[b];

    // ---- project 15 joints for the 2x2 (person, depth-half) tile ----
    float X[2][2][NJOINT], Y[2][2][NJOINT];
    #pragma unroll
    for (int pi = 0; pi < 2; ++pi) {
        #pragma unroll
        for (int dh = 0; dh < 2; ++dh) {
            const int d = lane + dh * 64;
            #pragma unroll
            for (int j = 0; j < NJOINT; ++j) {
                int base = (((b * NPERS + p0 + pi) * NJOINT + j) * NDEPTH + d) * 3;
                float a0 = poses_3d[base + 0] - T0;
                float a1 = poses_3d[base + 1] - T1;
                float a2 = poses_3d[base + 2] - T2;
                float xc0 = R00 * a0 + R01 * a1 + R02 * a2;
                float xc1 = R10 * a0 + R11 * a1 + R12 * a2;
                float xc2 = R20 * a0 + R21 * a1 + R22 * a2;
                float r   = __builtin_amdgcn_rcpf(xc2);
                X[pi][dh][j] = fmaf(fx * xc0, r, cx);
                Y[pi][dh][j] = fmaf(fy * xc1, r, cy);
            }
        }
    }

    // ---- partial argmin: this wave's 16-candidate slice, 4 combos ----
    float bv00 = 3.0e38f, bv01 = 3.0e38f, bv10 = 3.0e38f, bv11 = 3.0e38f;
    int   bq00 = 0, bq01 = 0, bq10 = 0, bq11 = 0;
    const int q0 = wv * QCHUNK;
    #pragma unroll 1
    for (int q = q0; q < q0 + QCHUNK; ++q) {
        float4 cw[4], cxr[4], cyr[4];
        #pragma unroll
        for (int k = 0; k < 4; ++k) {
            cw[k]  = sco[q][k];
            cxr[k] = sco[q][4 + k];
            cyr[k] = sco[q][8 + k];
        }
        const float c = cw[3].w;
        float a00 = c, a01 = c, a10 = c, a11 = c;
        #pragma unroll
        for (int j = 0; j < NJOINT; ++j) {
            float w  = CELEM(cw,  j);
            float wx = CELEM(cxr, j);
            float wy = CELEM(cyr, j);
            float u;
            u = fmaf(w, X[0][0][j], -wx); a00 = fmaf(X[0][0][j], u, a00);
            u = fmaf(w, Y[0][0][j], -wy); a00 = fmaf(Y[0][0][j], u, a00);
            u = fmaf(w, X[0][1][j], -wx); a01 = fmaf(X[0][1][j], u, a01);
            u = fmaf(w, Y[0][1][j], -wy); a01 = fmaf(Y[0][1][j], u, a01);
            u = fmaf(w, X[1][0][j], -wx); a10 = fmaf(X[1][0][j], u, a10);
            u = fmaf(w, Y[1][0][j], -wy); a10 = fmaf(Y[1][0][j], u, a10);
            u = fmaf(w, X[1][1][j], -wx); a11 = fmaf(X[1][1][j], u, a11);
            u = fmaf(w, Y[1][1][j], -wy); a11 = fmaf(Y[1][1][j], u, a11);
        }
        if (q >= npv) { a00 = BIGF; a01 = BIGF; a10 = BIGF; a11 = BIGF; }
        if (a00 < bv00) { bv00 = a00; bq00 = q; }   // ascending q, strict <
        if (a01 < bv01) { bv01 = a01; bq01 = q; }
        if (a10 < bv10) { bv10 = a10; bq10 = q; }
        if (a11 < bv11) { bv11 = a11; bq11 = q; }
    }
    // combo index: pi*2 + dh
    bvred[wv][0][lane] = bv00;  bqred[wv][0][lane] = bq00;
    bvred[wv][1][lane] = bv01;  bqred[wv][1][lane] = bq01;
    bvred[wv][2][lane] = bv10;  bqred[wv][2][lane] = bq10;
    bvred[wv][3][lane] = bv11;  bqred[wv][3][lane] = bq11;
    __syncthreads();

    // ---- each wave finishes ONE combo; STATIC unroll + uniform branch so
    //      X/Y indices stay compile-time (no scratch, rule #20) ----
    #pragma unroll
    for (int pi = 0; pi < 2; ++pi) {
        #pragma unroll
        for (int dh = 0; dh < 2; ++dh) {
            const int combo = pi * 2 + dh;
            if (wv == combo) {              // wave-uniform -> s_cbranch skip
                float bestv = 3.0e38f;
                int   bestq = 0;
                #pragma unroll
                for (int k = 0; k < QS; ++k) {   // ascending slice == asc. q
                    float v = bvred[k][combo][lane];
                    if (v < bestv) { bestv = v; bestq = bqred[k][combo][lane]; }
                }
                const int d = lane + dh * 64;
                const int obase = ((b * NPERS + p0 + pi) * NJOINT) * NDEPTH + d;
                #pragma unroll
                for (int j = 0; j < NJOINT; ++j) {
                    float4 v = sq[bestq][j];
                    float xx = X[pi][dh][j], yy = Y[pi][dh][j];
                    float dx = xx - v.y;
                    float dy = yy - v.z;
                    float md = fmaf(dx, dx, dy * dy);
                    float sc = __expf(-md * (1.0f / 225.0f));
                    float inb = (xx >= 0.0f && yy >= 0.0f &&
                                 xx <= iwm1 && yy <= ihm1) ? 1.0f : 0.0f;
                    out[obase + j * NDEPTH] = sc * inb * v.x;
                }
            }
        }
    }
}

extern "C" void kernel_launch(void* const* d_in, const int* in_sizes, int n_in,
                              void* d_out, int out_size, void* d_ws, size_t ws_size,
                              hipStream_t stream) {
    const float* poses_3d = (const float*)d_in[0];
    const float* p2d      = (const float*)d_in[1];
    const float* vis      = (const float*)d_in[2];
    const int*   nper     = (const int*)d_in[3];
    const float* Rm       = (const float*)d_in[4];
    const float* Tm       = (const float*)d_in[5];
    const float* fm       = (const float*)d_in[6];
    const float* cm       = (const float*)d_in[7];
    const float* iw       = (const float*)d_in[8];
    const float* ih       = (const float*)d_in[9];
    float* out = (float*)d_out;

    const int B = in_sizes[3];  // num_persons_ref has B elements
    dim3 grid(B * 32);          // (b, person-pair)
    dim3 block(256);            // 4 waves: q-slice x combo
    pose_match_kernel<<<grid, block, 0, stream>>>(
        poses_3d, p2d, vis, nper, Rm, Tm, fm, cm, iw, ih, out);
}